// Round 1
// baseline (319.484 us; speedup 1.0000x reference)
//
#include <hip/hip_runtime.h>

// CELoss_Marginal_Smooth: B=4194304 rows, C=12 classes, fp32.
// loss = ALPHA * ce + (1-ALPHA) * att_loss, reduced to a single scalar.
// Memory-bound: ~218 MB read once -> ~35 us floor at 6.3 TB/s.

#define CLS 12
#define ALPHA_F 0.6f

// att[i] = 1 / (# of 8-connected neighbors of cell i in a 3x4 grid)
__device__ __constant__ float ATT_TAB[CLS] = {
    1.0f/3.0f, 1.0f/5.0f, 1.0f/5.0f, 1.0f/3.0f,
    1.0f/5.0f, 1.0f/8.0f, 1.0f/8.0f, 1.0f/5.0f,
    1.0f/3.0f, 1.0f/5.0f, 1.0f/5.0f, 1.0f/3.0f
};

__global__ __launch_bounds__(256)
void ce_marginal_smooth_kernel(const float* __restrict__ outputs,
                               const int*   __restrict__ targets,
                               float* __restrict__ out,
                               int B, float inv_b)
{
    const int tid    = blockIdx.x * blockDim.x + threadIdx.x;
    const int stride = gridDim.x * blockDim.x;

    float acc = 0.0f;

    for (int row = tid; row < B; row += stride) {
        // Row = 48 contiguous bytes; load as 3 x float4.
        const float4* p = reinterpret_cast<const float4*>(outputs) + (size_t)row * 3;
        float4 f0 = p[0];
        float4 f1 = p[1];
        float4 f2 = p[2];
        float x[CLS] = { f0.x, f0.y, f0.z, f0.w,
                         f1.x, f1.y, f1.z, f1.w,
                         f2.x, f2.y, f2.z, f2.w };

        // log-sum-exp with max subtraction
        float m = x[0];
        #pragma unroll
        for (int j = 1; j < CLS; ++j) m = fmaxf(m, x[j]);

        float se = 0.0f, rs = 0.0f;
        #pragma unroll
        for (int j = 0; j < CLS; ++j) {
            se += __expf(x[j] - m);
            rs += x[j];
        }
        float lse = m + __logf(se);

        int t = targets[row];
        // register-array select via cndmask chain (no scratch)
        float xt = x[0];
        #pragma unroll
        for (int j = 1; j < CLS; ++j) xt = (t == j) ? x[j] : xt;

        float logp_t  = xt - lse;
        float row_sum = rs - (float)CLS * lse;
        float att     = ATT_TAB[t];

        // v = ALPHA*(-logp_t) + (1-ALPHA)*(-(att*(row_sum - logp_t) + logp_t))
        float v = -ALPHA_F * logp_t
                  - (1.0f - ALPHA_F) * (att * (row_sum - logp_t) + logp_t);
        acc += v;
    }

    acc *= inv_b;

    // wave64 butterfly reduce
    #pragma unroll
    for (int off = 32; off > 0; off >>= 1)
        acc += __shfl_down(acc, off, 64);

    if ((threadIdx.x & 63) == 0)
        atomicAdd(out, acc);
}

extern "C" void kernel_launch(void* const* d_in, const int* in_sizes, int n_in,
                              void* d_out, int out_size, void* d_ws, size_t ws_size,
                              hipStream_t stream)
{
    const float* outputs = (const float*)d_in[0];
    const int*   targets = (const int*)d_in[1];
    float*       out     = (float*)d_out;

    const int B = in_sizes[1];          // number of rows (targets element count)
    const float inv_b = 1.0f / (float)B;

    // d_out is poisoned to 0xAA before every timed launch — zero it (async, capture-safe).
    hipMemsetAsync(out, 0, sizeof(float), stream);

    const int block = 256;
    const int grid  = 1024;             // grid-stride, ~16 rows/thread
    ce_marginal_smooth_kernel<<<grid, block, 0, stream>>>(outputs, targets, out, B, inv_b);
}

// Round 2
// 289.525 us; speedup vs baseline: 1.1035x; 1.1035x over previous
//
#include <hip/hip_runtime.h>

// CELoss_Marginal_Smooth: B=4194304 rows, C=12 classes, fp32 -> scalar loss.
// Memory-bound streaming: ~218 MB input (L3 retains ~half across replays).
// R1 post-mortem: 119us was latency-bound (occ 36%, VALUBusy 11%) -> raise
// MLP: 2048 blocks (full 32 waves/CU) + unroll-4 independent row iterations.

#define CLS 12
#define ALPHA_F 0.6f

// att[i] = 1 / (# of 8-connected neighbors of cell i in a 3x4 grid)
__device__ __constant__ float ATT_TAB[CLS] = {
    1.0f/3.0f, 1.0f/5.0f, 1.0f/5.0f, 1.0f/3.0f,
    1.0f/5.0f, 1.0f/8.0f, 1.0f/8.0f, 1.0f/5.0f,
    1.0f/3.0f, 1.0f/5.0f, 1.0f/5.0f, 1.0f/3.0f
};

__device__ __forceinline__ float row_loss(const float* __restrict__ outputs,
                                          const int*   __restrict__ targets,
                                          int row)
{
    const float4* p = reinterpret_cast<const float4*>(outputs) + (size_t)row * 3;
    float4 f0 = p[0];
    float4 f1 = p[1];
    float4 f2 = p[2];
    int t = targets[row];

    float x[CLS] = { f0.x, f0.y, f0.z, f0.w,
                     f1.x, f1.y, f1.z, f1.w,
                     f2.x, f2.y, f2.z, f2.w };

    float m = x[0];
    #pragma unroll
    for (int j = 1; j < CLS; ++j) m = fmaxf(m, x[j]);

    float se = 0.0f, rs = 0.0f;
    #pragma unroll
    for (int j = 0; j < CLS; ++j) {
        se += __expf(x[j] - m);
        rs += x[j];
    }
    float lse = m + __logf(se);

    float xt = x[0];
    #pragma unroll
    for (int j = 1; j < CLS; ++j) xt = (t == j) ? x[j] : xt;

    float logp_t  = xt - lse;
    float row_sum = rs - (float)CLS * lse;
    float att     = ATT_TAB[t];

    return -ALPHA_F * logp_t
           - (1.0f - ALPHA_F) * (att * (row_sum - logp_t) + logp_t);
}

__global__ __launch_bounds__(256)
void ce_marginal_smooth_kernel(const float* __restrict__ outputs,
                               const int*   __restrict__ targets,
                               float* __restrict__ out,
                               int B, float inv_b)
{
    const int tid      = blockIdx.x * blockDim.x + threadIdx.x;
    const int nthreads = gridDim.x * blockDim.x;

    float acc = 0.0f;

    // Counted main loop: independent iterations, unrolled for MLP so the
    // compiler batches many global_load_dwordx4 before the first waitcnt.
    const int full = B / nthreads;
    #pragma unroll 4
    for (int it = 0; it < full; ++it) {
        acc += row_loss(outputs, targets, tid + it * nthreads);
    }
    // tail (empty when nthreads divides B)
    for (int row = tid + full * nthreads; row < B; row += nthreads) {
        acc += row_loss(outputs, targets, row);
    }

    acc *= inv_b;

    // wave64 butterfly reduce
    #pragma unroll
    for (int off = 32; off > 0; off >>= 1)
        acc += __shfl_down(acc, off, 64);

    // block reduce via LDS: one atomic per block
    __shared__ float warp_part[4];
    const int wave = threadIdx.x >> 6;
    if ((threadIdx.x & 63) == 0) warp_part[wave] = acc;
    __syncthreads();
    if (threadIdx.x == 0) {
        float s = warp_part[0] + warp_part[1] + warp_part[2] + warp_part[3];
        atomicAdd(out, s);
    }
}

extern "C" void kernel_launch(void* const* d_in, const int* in_sizes, int n_in,
                              void* d_out, int out_size, void* d_ws, size_t ws_size,
                              hipStream_t stream)
{
    const float* outputs = (const float*)d_in[0];
    const int*   targets = (const int*)d_in[1];
    float*       out     = (float*)d_out;

    const int B = in_sizes[1];
    const float inv_b = 1.0f / (float)B;

    hipMemsetAsync(out, 0, sizeof(float), stream);

    const int block = 256;
    const int grid  = 2048;   // 8 wg/CU -> full 32 waves/CU, 8 rows/thread
    ce_marginal_smooth_kernel<<<grid, block, 0, stream>>>(outputs, targets, out, B, inv_b);
}

// Round 3
// 286.272 us; speedup vs baseline: 1.1160x; 1.0114x over previous
//
#include <hip/hip_runtime.h>

// CELoss_Marginal_Smooth: B=4194304 rows, C=12 classes, fp32 -> scalar loss.
// R2 post-mortem: VGPR=16 proves the compiler register-recycled the unrolled
// loop -> only ~3 loads in flight per wave -> latency-bound (~90us vs ~35us
// floor). Fix: no loop. 4 rows/thread held in named registers, all 16 loads
// issued before any compute. 4096 blocks x 256 thr x 4 rows = B exactly.

#define CLS 12
#define ALPHA_F 0.6f

// att[i] = 1 / (# of 8-connected neighbors of cell i in a 3x4 grid)
__device__ __constant__ float ATT_TAB[CLS] = {
    1.0f/3.0f, 1.0f/5.0f, 1.0f/5.0f, 1.0f/3.0f,
    1.0f/5.0f, 1.0f/8.0f, 1.0f/8.0f, 1.0f/5.0f,
    1.0f/3.0f, 1.0f/5.0f, 1.0f/5.0f, 1.0f/3.0f
};

__device__ __forceinline__ float row_loss_compute(float4 f0, float4 f1, float4 f2, int t)
{
    float x[CLS] = { f0.x, f0.y, f0.z, f0.w,
                     f1.x, f1.y, f1.z, f1.w,
                     f2.x, f2.y, f2.z, f2.w };

    float m = x[0];
    #pragma unroll
    for (int j = 1; j < CLS; ++j) m = fmaxf(m, x[j]);

    float se = 0.0f, rs = 0.0f;
    #pragma unroll
    for (int j = 0; j < CLS; ++j) {
        se += __expf(x[j] - m);
        rs += x[j];
    }
    float lse = m + __logf(se);

    float xt = x[0];
    #pragma unroll
    for (int j = 1; j < CLS; ++j) xt = (t == j) ? x[j] : xt;

    float logp_t  = xt - lse;
    float row_sum = rs - (float)CLS * lse;
    float att     = ATT_TAB[t];

    return -ALPHA_F * logp_t
           - (1.0f - ALPHA_F) * (att * (row_sum - logp_t) + logp_t);
}

__global__ __launch_bounds__(256)
void ce_marginal_smooth_kernel(const float* __restrict__ outputs,
                               const int*   __restrict__ targets,
                               float* __restrict__ out,
                               int B, float inv_b)
{
    // Each block owns a contiguous 1024-row chunk; thread handles 4 rows
    // spaced 256 apart inside the chunk (coalesced per-instruction).
    const int base = blockIdx.x * 1024 + threadIdx.x;
    const int r0 = base;
    const int r1 = base + 256;
    const int r2 = base + 512;
    const int r3 = base + 768;

    float acc = 0.0f;

    if (r3 < B) {
        const float4* p = reinterpret_cast<const float4*>(outputs);
        // All 16 loads issued before any consuming compute (values all live).
        float4 a0 = p[(size_t)r0 * 3 + 0], a1 = p[(size_t)r0 * 3 + 1], a2 = p[(size_t)r0 * 3 + 2];
        float4 b0 = p[(size_t)r1 * 3 + 0], b1 = p[(size_t)r1 * 3 + 1], b2 = p[(size_t)r1 * 3 + 2];
        float4 c0 = p[(size_t)r2 * 3 + 0], c1 = p[(size_t)r2 * 3 + 1], c2 = p[(size_t)r2 * 3 + 2];
        float4 d0 = p[(size_t)r3 * 3 + 0], d1 = p[(size_t)r3 * 3 + 1], d2 = p[(size_t)r3 * 3 + 2];
        int t0 = targets[r0], t1 = targets[r1], t2 = targets[r2], t3 = targets[r3];

        acc += row_loss_compute(a0, a1, a2, t0);
        acc += row_loss_compute(b0, b1, b2, t1);
        acc += row_loss_compute(c0, c1, c2, t2);
        acc += row_loss_compute(d0, d1, d2, t3);
    } else {
        // generic tail (unused when B == grid*block*4)
        const float4* p = reinterpret_cast<const float4*>(outputs);
        int rows[4] = { r0, r1, r2, r3 };
        for (int k = 0; k < 4; ++k) {
            int r = rows[k];
            if (r < B) {
                float4 f0 = p[(size_t)r * 3 + 0];
                float4 f1 = p[(size_t)r * 3 + 1];
                float4 f2 = p[(size_t)r * 3 + 2];
                acc += row_loss_compute(f0, f1, f2, targets[r]);
            }
        }
    }

    acc *= inv_b;

    // wave64 butterfly reduce
    #pragma unroll
    for (int off = 32; off > 0; off >>= 1)
        acc += __shfl_down(acc, off, 64);

    // block reduce via LDS: one atomic per block
    __shared__ float warp_part[4];
    const int wave = threadIdx.x >> 6;
    if ((threadIdx.x & 63) == 0) warp_part[wave] = acc;
    __syncthreads();
    if (threadIdx.x == 0) {
        float s = warp_part[0] + warp_part[1] + warp_part[2] + warp_part[3];
        atomicAdd(out, s);
    }
}

extern "C" void kernel_launch(void* const* d_in, const int* in_sizes, int n_in,
                              void* d_out, int out_size, void* d_ws, size_t ws_size,
                              hipStream_t stream)
{
    const float* outputs = (const float*)d_in[0];
    const int*   targets = (const int*)d_in[1];
    float*       out     = (float*)d_out;

    const int B = in_sizes[1];
    const float inv_b = 1.0f / (float)B;

    hipMemsetAsync(out, 0, sizeof(float), stream);

    const int block = 256;
    const int grid  = (B + block * 4 - 1) / (block * 4);   // 4096 for B=4M
    ce_marginal_smooth_kernel<<<grid, block, 0, stream>>>(outputs, targets, out, B, inv_b);
}